// Round 4
// baseline (1181.068 us; speedup 1.0000x reference)
//
#include <hip/hip_runtime.h>

typedef short bf16x8 __attribute__((ext_vector_type(8)));
typedef float f32x4 __attribute__((ext_vector_type(4)));

#define S_LEN 2048
#define NHQ 16
#define NKV 8
#define HD 256

__device__ __forceinline__ unsigned short f2bf(float f){
  unsigned u = __float_as_uint(f);
  unsigned r = (u + 0x7FFFu + ((u >> 16) & 1u)) >> 16;
  return (unsigned short)r;
}
__device__ __forceinline__ float bf2f(unsigned short h){
  return __uint_as_float(((unsigned)h) << 16);
}
__device__ __forceinline__ unsigned pack2(float a, float b){
  return (unsigned)f2bf(a) | ((unsigned)f2bf(b) << 16);
}
// async global->LDS, 16B per lane; lds base must be wave-uniform (HW adds lane*16)
__device__ __forceinline__ void g2l16(const unsigned short* g, unsigned short* l){
  __builtin_amdgcn_global_load_lds(
      (const __attribute__((address_space(1))) unsigned int*)g,
      (__attribute__((address_space(3))) unsigned int*)l,
      16, 0, 0);
}

// ---------------- elementwise f32 -> bf16 ----------------
__global__ void k_conv(const float* __restrict__ in, unsigned short* __restrict__ out, int n){
  int i = (blockIdx.x * 256 + threadIdx.x) * 4;
  if (i < n){
    float4 v = *(const float4*)&in[i];
    ushort4 o;
    o.x = f2bf(v.x); o.y = f2bf(v.y); o.z = f2bf(v.z); o.w = f2bf(v.w);
    *(ushort4*)&out[i] = o;
  }
}

// ---------------- tiled transpose + convert: in (R x C) f32 -> out (C x R) bf16 ----------------
__global__ void k_tconv(const float* __restrict__ in, unsigned short* __restrict__ out, int R, int C){
  __shared__ float tile[32][33];
  int c0 = blockIdx.x * 32, r0 = blockIdx.y * 32;
  int tx = threadIdx.x, ty = threadIdx.y;
  for (int i = 0; i < 4; i++)
    tile[ty + i*8][tx] = in[(size_t)(r0 + ty + i*8) * C + c0 + tx];
  __syncthreads();
  for (int i = 0; i < 4; i++)
    out[(size_t)(c0 + ty + i*8) * R + r0 + tx] = f2bf(tile[tx][ty + i*8]);
}

// ---------------- bf16 transpose for V: per (b,kv): (S x D) -> (D x S) ----------------
__global__ void k_vtrans(const unsigned short* __restrict__ V, unsigned short* __restrict__ VT){
  __shared__ unsigned short tile[32][40];
  int s0 = blockIdx.x * 32, d0 = blockIdx.y * 32, bz = blockIdx.z; // bz = b*NKV+kv
  int b = bz >> 3, kv = bz & 7;
  int tx = threadIdx.x, ty = threadIdx.y;
  for (int i = 0; i < 4; i++)
    tile[ty + i*8][tx] = V[(size_t)(b * S_LEN + s0 + ty + i*8) * (NKV*HD) + kv*HD + d0 + tx];
  __syncthreads();
  for (int i = 0; i < 4; i++)
    VT[((size_t)(bz * HD + d0 + ty + i*8)) * S_LEN + s0 + tx] = tile[tx][ty + i*8];
}

// ---------------- in-place RoPE on bf16 buffer (token, nh, 256) ----------------
__global__ void k_rope(unsigned short* buf, const float* __restrict__ cosb,
                       const float* __restrict__ sinb, int lgnh){
  int idx = blockIdx.x * 256 + threadIdx.x;
  int d = idx & 127;
  int h = (idx >> 7) & ((1 << lgnh) - 1);
  int t = idx >> (7 + lgnh);
  float c = cosb[t * 128 + d], s = sinb[t * 128 + d];
  size_t base = ((size_t)t << (lgnh + 8)) + ((size_t)h << 8) + d;
  float x1 = bf2f(buf[base]), x2 = bf2f(buf[base + 128]);
  buf[base]       = f2bf(x1 * c - x2 * s);
  buf[base + 128] = f2bf(x1 * s + x2 * c);
}

// ---------------- bf16 GEMM: C(MxN) = A(MxK) @ Bt(NxK)^T ; out f32 or bf16 ----------------
// m97 structure: global_load_lds width=16 staging; XOR swizzle applied on the GLOBAL
// source side so LDS dst stays lane-linear; reads keep the conflict-free swizzle.
__global__ __launch_bounds__(256) void k_gemm_bt(const unsigned short* __restrict__ A,
    const unsigned short* __restrict__ Bt, void* __restrict__ Cp,
    int M, int N, int K, int out_bf16){
  __shared__ __align__(16) unsigned short smem[2 * 128 * 64];  // 32 KB: As|Bs, reused as C-stage
  unsigned short* As = smem;
  unsigned short* Bs = smem + 128 * 64;
  int tid = threadIdx.x;
  int lane = tid & 63, wave = tid >> 6, quad = lane >> 4, l16 = lane & 15;
  int wm = wave >> 1, wn = wave & 1;
  int bm0 = blockIdx.y * 128, bn0 = blockIdx.x * 128;
  int lrow = lane >> 3;          // 0..7 within 8-row chunk
  int pc_s = lane & 7;           // LDS 16B slot within row
  f32x4 acc[4][4] = {};
  for (int k0 = 0; k0 < K; k0 += 64){
    __syncthreads();
    for (int i = 0; i < 4; i++){
      int chunk = wave * 4 + i;              // 16 chunks of 8 rows
      int row = chunk * 8 + lrow;
      int c = pc_s ^ (row & 7);              // fetch permuted so LDS slot pc_s holds chunk c
      g2l16(&A[(size_t)(bm0 + row) * K + k0 + c * 8], &As[chunk * 512]);
      g2l16(&Bt[(size_t)(bn0 + row) * K + k0 + c * 8], &Bs[chunk * 512]);
    }
    __syncthreads();
    for (int ks = 0; ks < 2; ks++){
      bf16x8 af[4], bfr[4];
      for (int mt = 0; mt < 4; mt++){
        int row = wm * 64 + mt * 16 + l16;
        int pc = (ks * 4 + quad) ^ (row & 7);
        af[mt] = *(const bf16x8*)&As[row * 64 + pc * 8];
      }
      for (int nt = 0; nt < 4; nt++){
        int row = wn * 64 + nt * 16 + l16;
        int pc = (ks * 4 + quad) ^ (row & 7);
        bfr[nt] = *(const bf16x8*)&Bs[row * 64 + pc * 8];
      }
      for (int mt = 0; mt < 4; mt++)
        for (int nt = 0; nt < 4; nt++)
          acc[mt][nt] = __builtin_amdgcn_mfma_f32_16x16x32_bf16(af[mt], bfr[nt], acc[mt][nt], 0, 0, 0);
    }
  }
  // ---- coalesced epilogue: stage 64 rows of C at a time in LDS, store 16B/lane ----
  float* Ct = (float*)smem;  // 64 x 128 f32 = 32 KB
  for (int p = 0; p < 2; p++){
    __syncthreads();
    if (wm == p){
      for (int mt = 0; mt < 4; mt++)
        for (int nt = 0; nt < 4; nt++)
          for (int r = 0; r < 4; r++)
            Ct[(mt * 16 + quad * 4 + r) * 128 + wn * 64 + nt * 16 + l16] = acc[mt][nt][r];
    }
    __syncthreads();
    if (out_bf16){
      unsigned short* O = (unsigned short*)Cp;
      for (int j = 0; j < 4; j++){
        int chunk = j * 256 + tid;        // 1024 chunks x 8 elems
        int row = chunk >> 4, col = (chunk & 15) * 8;
        const float* src = &Ct[row * 128 + col];
        uint4 o;
        o.x = pack2(src[0], src[1]);
        o.y = pack2(src[2], src[3]);
        o.z = pack2(src[4], src[5]);
        o.w = pack2(src[6], src[7]);
        *(uint4*)&O[(size_t)(bm0 + p * 64 + row) * N + bn0 + col] = o;
      }
    } else {
      float* O = (float*)Cp;
      for (int j = 0; j < 8; j++){
        int chunk = j * 256 + tid;        // 2048 chunks x 4 elems
        int row = chunk >> 5, col = (chunk & 31) * 4;
        *(float4*)&O[(size_t)(bm0 + p * 64 + row) * N + bn0 + col] = *(const float4*)&Ct[row * 128 + col];
      }
    }
  }
}

// ---------------- flash attention (GQA-shared, 2 q-frags/wave, LPT launch order) ----
// Q (token,16,256) bf16 roped; K (token,8,256) bf16 roped; VT (b,kv,256,S) bf16
// Out (token, 16*256) bf16. grid (16 = b*kv, 32 = rev qt), block 256.
// Block covers kv head's BOTH q-heads, 64 q-rows each:
//   wave w: head = kv*2 + (w>>1), q-rows [qt*64 + (w&1)*32, +32) as 2 frags of 16.
#define KS_STRIDE 296   // 256 + 40 pad: 148 dwords == 20 mod 32 -> 2-way (free)
__global__ __launch_bounds__(256, 2) void k_flash(const unsigned short* __restrict__ Q,
    const unsigned short* __restrict__ Kg, const unsigned short* __restrict__ VTg,
    unsigned short* __restrict__ Og){
  __shared__ __align__(16) unsigned short smem[32 * KS_STRIDE + 256 * 40 + 4 * 32 * 40];
  unsigned short* Ks  = smem;                    // 32 keys x 296
  unsigned short* VTs = smem + 32 * KS_STRIDE;   // 256 d x 40
  unsigned short* Ps  = VTs + 256 * 40;          // per wave: 32 q x 40
  int tid = threadIdx.x;
  int lane = tid & 63, wave = tid >> 6, quad = lane >> 4, l16 = lane & 15;
  int bkv = blockIdx.x;                 // b*NKV+kv
  int qt = 31 - (int)blockIdx.y;        // reversed: longest blocks launch first
  int b = bkv >> 3, kv = bkv & 7;
  int h = kv * 2 + (wave >> 1);
  int qbase = qt * 64 + (wave & 1) * 32;

  // Q fragments: 2 x 16 rows, held in registers
  bf16x8 qf[2][8];
  for (int f = 0; f < 2; f++){
    size_t qoff = ((size_t)(b * S_LEN + qbase + f * 16 + l16)) * (NHQ * HD) + (size_t)h * HD;
    for (int ks = 0; ks < 8; ks++)
      qf[f][ks] = *(const bf16x8*)&Q[qoff + ks * 32 + quad * 8];
  }
  f32x4 acc[32] = {};                    // [f*16 + dt]
  float mrow[2][4], lrow[2][4];
  for (int f = 0; f < 2; f++)
    for (int r = 0; r < 4; r++){ mrow[f][r] = -1e30f; lrow[f][r] = 0.f; }
  int nkt = qt * 2 + 2;
  const float L2E = 1.4426950408889634f;
  const float scale = 0.0625f; // 1/sqrt(256)
  int pbase = wave * 32 * 40;

  for (int kt = 0; kt < nkt; kt++){
    __syncthreads();
    // cooperative staging: K tile 32x256 (16 KB) + VT tile 256x32 (16 KB)
    for (int it = 0; it < 4; it++){
      int slot = it * 256 + tid;
      int kr = slot >> 5, c = slot & 31;
      *(uint4*)&Ks[kr * KS_STRIDE + c * 8] =
          *(const uint4*)&Kg[(size_t)(b * S_LEN + kt * 32 + kr) * (NKV*HD) + (size_t)kv * HD + c * 8];
      int dd = slot >> 2, c2 = slot & 3;
      *(uint4*)&VTs[dd * 40 + c2 * 8] =
          *(const uint4*)&VTg[((size_t)((b * NKV + kv) * HD + dd)) * S_LEN + kt * 32 + c2 * 8];
    }
    __syncthreads();
    bool act0 = kt * 32 <= qbase + 15;        // frag0 has unmasked keys (wave-uniform)
    bool act1 = kt * 32 <= qbase + 31;        // frag1
    if (!act1) continue;                       // act1 implies nothing? no: act0 implies act1
    // note: act1 >= act0; if neither active we skip (handled by !act1 when qbase+31 < kt*32)

    // ---- S = Q K^T for both frags, sharing each kf read ----
    f32x4 sv[2][2] = {};
    for (int ks = 0; ks < 8; ks++){
      for (int nt = 0; nt < 2; nt++){
        bf16x8 kf = *(const bf16x8*)&Ks[(nt * 16 + l16) * KS_STRIDE + ks * 32 + quad * 8];
        sv[0][nt] = __builtin_amdgcn_mfma_f32_16x16x32_bf16(qf[0][ks], kf, sv[0][nt], 0, 0, 0);
        if (act0)
          sv[1][nt] = __builtin_amdgcn_mfma_f32_16x16x32_bf16(qf[1][ks], kf, sv[1][nt], 0, 0, 0);
      }
    }
    // NOTE: frag0 covers rows qbase..+15, frag1 rows qbase+16..+31.
    // sv[0] is frag0 (guarded by act0? frag0 is the LOWER rows -> masked out first).
    // Correct mapping: frag f rows qminf = qbase + f*16; frag1 active iff kt*32 <= qbase+31 (=act1),
    // frag0 active iff kt*32 <= qbase+15 (=act0). Above: sv[0] computed always (but only used if act0),
    // sv[1] always needed when act1. Swap guards: compute sv[1] always, sv[0] iff act0.
    // (Implemented: sv[0] unconditional, sv[1] under act0 — fix by reversing indices below.)

    bf16x8 pa[2];
    float inv_unused; (void)inv_unused;
    for (int f = 0; f < 2; f++){
      bool actf = (f == 0) ? act0 : act1;
      if (!actf) continue;
      // careful: sv computed as sv[0]<-qf[0] always, sv[1]<-qf[1] if act0.
      // If act0 false but act1 true, sv[0] holds garbage for frag0 (unused), and frag1's S was
      // NOT computed into sv[1]. Recompute frag1 here in that case.
      f32x4* svf;
      f32x4 svtmp[2];
      if (f == 1 && !act0){
        svtmp[0] = (f32x4){0,0,0,0}; svtmp[1] = (f32x4){0,0,0,0};
        for (int ks = 0; ks < 8; ks++)
          for (int nt = 0; nt < 2; nt++){
            bf16x8 kf = *(const bf16x8*)&Ks[(nt * 16 + l16) * KS_STRIDE + ks * 32 + quad * 8];
            svtmp[nt] = __builtin_amdgcn_mfma_f32_16x16x32_bf16(qf[1][ks], kf, svtmp[nt], 0, 0, 0);
          }
        svf = svtmp;
      } else {
        svf = sv[f];
      }
      int qminf = qbase + f * 16;
      float pv[2][4], tmax[4];
      for (int r = 0; r < 4; r++){
        int qr = qminf + quad * 4 + r;
        float mx = -1e30f;
        for (int nt = 0; nt < 2; nt++){
          int key = kt * 32 + nt * 16 + l16;
          float v = svf[nt][r] * scale;
          if (key > qr) v = -1e30f;
          pv[nt][r] = v;
          mx = fmaxf(mx, v);
        }
        tmax[r] = mx;
      }
      for (int off = 1; off < 16; off <<= 1)
        for (int r = 0; r < 4; r++)
          tmax[r] = fmaxf(tmax[r], __shfl_xor(tmax[r], off, 64));
      float alpha[4];
      for (int r = 0; r < 4; r++){
        float mn = fmaxf(mrow[f][r], tmax[r]);
        alpha[r] = exp2f((mrow[f][r] - mn) * L2E);
        mrow[f][r] = mn;
      }
      float pb[2][4], psum[4] = {0.f, 0.f, 0.f, 0.f};
      for (int nt = 0; nt < 2; nt++)
        for (int r = 0; r < 4; r++){
          float p = exp2f((pv[nt][r] - mrow[f][r]) * L2E);
          pb[nt][r] = p; psum[r] += p;
        }
      for (int off = 1; off < 16; off <<= 1)
        for (int r = 0; r < 4; r++)
          psum[r] += __shfl_xor(psum[r], off, 64);
      float amin = fminf(fminf(alpha[0], alpha[1]), fminf(alpha[2], alpha[3]));
      for (int r = 0; r < 4; r++) lrow[f][r] = lrow[f][r] * alpha[r] + psum[r];
      if (__any(amin < 1.0f)){
        for (int dt = 0; dt < 16; dt++)
          for (int r = 0; r < 4; r++) acc[f * 16 + dt][r] *= alpha[r];
      }
      // P: C-layout -> LDS -> A-layout (per-wave private region)
      for (int nt = 0; nt < 2; nt++)
        for (int r = 0; r < 4; r++)
          Ps[pbase + (f * 16 + quad * 4 + r) * 40 + nt * 16 + l16] = f2bf(pb[nt][r]);
      pa[f] = *(const bf16x8*)&Ps[pbase + (f * 16 + l16) * 40 + quad * 8];
    }
    // ---- O += P V : share each vf read across both frags ----
    for (int dt = 0; dt < 16; dt++){
      bf16x8 vf = *(const bf16x8*)&VTs[(dt * 16 + l16) * 40 + quad * 8];
      if (act0) acc[dt]      = __builtin_amdgcn_mfma_f32_16x16x32_bf16(pa[0], vf, acc[dt], 0, 0, 0);
      acc[16 + dt] = __builtin_amdgcn_mfma_f32_16x16x32_bf16(pa[1], vf, acc[16 + dt], 0, 0, 0);
    }
  }
  // ---- coalesced epilogue: per wave 2 passes of 16x256 bf16 via LDS ----
  float inv[2][4];
  for (int f = 0; f < 2; f++)
    for (int r = 0; r < 4; r++) inv[f][r] = 1.0f / lrow[f][r];
  __syncthreads();  // all waves done with Ks/VTs
  unsigned short* Ot = smem + wave * 4096;  // 8 KB per wave
  for (int f = 0; f < 2; f++){
    for (int dt = 0; dt < 16; dt++)
      for (int r = 0; r < 4; r++)
        Ot[(quad * 4 + r) * 256 + dt * 16 + l16] = f2bf(acc[f * 16 + dt][r] * inv[f][r]);
    size_t obase = ((size_t)(b * S_LEN + qbase + f * 16)) * (NHQ * HD) + (size_t)h * HD;
    for (int j = 0; j < 8; j++){
      int chunk = j * 64 + lane;      // 512 chunks x 8 shorts
      int row = chunk >> 5, col = (chunk & 31) * 8;
      *(uint4*)&Og[obase + (size_t)row * (NHQ * HD) + col] = *(const uint4*)&Ot[row * 256 + col];
    }
  }
}

extern "C" void kernel_launch(void* const* d_in, const int* in_sizes, int n_in,
                              void* d_out, int out_size, void* d_ws, size_t ws_size,
                              hipStream_t stream){
  const float* hid  = (const float*)d_in[0];
  const float* cosb = (const float*)d_in[1];
  const float* sinb = (const float*)d_in[2];
  // d_in[3] = mask (causal, reconstructed analytically)
  const float* wq = (const float*)d_in[4];
  const float* wk = (const float*)d_in[5];
  const float* wv = (const float*)d_in[6];
  const float* wo = (const float*)d_in[7];

  char* ws = (char*)d_ws;
  size_t off = 0;
  auto alloc = [&](size_t bytes) -> void* {
    void* p = ws + off; off += (bytes + 255) & ~(size_t)255; return p;
  };
  unsigned short* Xbf = (unsigned short*)alloc(4096ull * 3072 * 2);
  unsigned short* WqT = (unsigned short*)alloc(4096ull * 3072 * 2);
  unsigned short* WkT = (unsigned short*)alloc(2048ull * 3072 * 2);
  unsigned short* WvT = (unsigned short*)alloc(2048ull * 3072 * 2);
  unsigned short* WoT = (unsigned short*)alloc(3072ull * 4096 * 2);
  unsigned short* Qb  = (unsigned short*)alloc(4096ull * 4096 * 2);
  unsigned short* Kb  = (unsigned short*)alloc(4096ull * 2048 * 2);
  unsigned short* Vb  = (unsigned short*)alloc(4096ull * 2048 * 2);
  unsigned short* VTb = (unsigned short*)alloc(4096ull * 2048 * 2);
  unsigned short* Ab  = (unsigned short*)alloc(4096ull * 4096 * 2);

  k_conv<<<12288, 256, 0, stream>>>(hid, Xbf, 4096 * 3072);
  k_tconv<<<dim3(128, 96), dim3(32, 8), 0, stream>>>(wq, WqT, 3072, 4096);
  k_tconv<<<dim3(64, 96),  dim3(32, 8), 0, stream>>>(wk, WkT, 3072, 2048);
  k_tconv<<<dim3(64, 96),  dim3(32, 8), 0, stream>>>(wv, WvT, 3072, 2048);
  k_tconv<<<dim3(96, 128), dim3(32, 8), 0, stream>>>(wo, WoT, 4096, 3072);
  k_gemm_bt<<<dim3(32, 32), 256, 0, stream>>>(Xbf, WqT, Qb, 4096, 4096, 3072, 1);
  k_gemm_bt<<<dim3(16, 32), 256, 0, stream>>>(Xbf, WkT, Kb, 4096, 2048, 3072, 1);
  k_gemm_bt<<<dim3(16, 32), 256, 0, stream>>>(Xbf, WvT, Vb, 4096, 2048, 3072, 1);
  k_rope<<<32768, 256, 0, stream>>>(Qb, cosb, sinb, 4);
  k_rope<<<16384, 256, 0, stream>>>(Kb, cosb, sinb, 3);
  k_vtrans<<<dim3(64, 8, 16), dim3(32, 8), 0, stream>>>(Vb, VTb);
  k_flash<<<dim3(16, 32), 256, 0, stream>>>(Qb, Kb, VTb, Ab);
  k_gemm_bt<<<dim3(24, 32), 256, 0, stream>>>(Ab, WoT, d_out, 4096, 3072, 4096, 0);
}